// Round 3
// baseline (256.301 us; speedup 1.0000x reference)
//
#include <hip/hip_runtime.h>
#include <math.h>

#define BB 4
#define DL 150
#define PL 1000
#define CD 64
#define NC1 40
#define NC2 80
#define NC3 160
#define L1O 997
#define L2O 990
#define L3O 979
#define L1P 1000
#define L2P 992
#define L3P 980
#define DLP 152
#define PLP 984
#define NINF (-1e30f)

__device__ __forceinline__ float relu_(float x){ return fmaxf(x, 0.f); }
__device__ __forceinline__ float lrelu_(float x){ return x > 0.f ? x : 0.01f * x; }

__device__ __forceinline__ unsigned fenc(float x){
  unsigned u = __float_as_uint(x);
  return (u & 0x80000000u) ? ~u : (u | 0x80000000u);
}
__device__ __forceinline__ float fdec(unsigned u){
  return __uint_as_float((u & 0x80000000u) ? (u & 0x7fffffffu) : ~u);
}

// ---- proj table: proj[tok][k][co] = sum_ci emb[tok][ci] * w1[co][ci][k] ----
__global__ void k_proj(const float* __restrict__ emb, const float* __restrict__ w1,
                       float* __restrict__ projG){
  int e = blockIdx.x * 256 + threadIdx.x;
  if (e >= 26 * 160) return;
  int tok = e / 160, rem = e % 160, k = rem / 40, co = rem % 40;
  float a = 0.f;
  const float* er = emb + tok * CD;
  const float* wr = w1 + co * (CD * 4) + k;
  #pragma unroll 8
  for (int ci = 0; ci < CD; ci++) a = fmaf(er[ci], wr[ci * 4], a);
  projG[tok * 161 + k * 40 + co] = a;
}

// ---- conv1 apply ----
__global__ __launch_bounds__(256) void k_conv1(const int* __restrict__ prot,
                        const float* __restrict__ projG, const float* __restrict__ b1,
                        float* __restrict__ h1){
  __shared__ float sp[26 * 161];
  int b = blockIdx.x / 80;
  int t = (blockIdx.x % 80) * 256 + threadIdx.x;
  for (int k = threadIdx.x; k < 26 * 161; k += 256) sp[k] = projG[k];
  __syncthreads();
  int p = t & 1023, co2 = t >> 10;
  if (p >= L1O) return;
  const int* pr = prot + b * PL + p;
  int t0 = pr[0], t1 = pr[1], t2 = pr[2], t3 = pr[3];
  #pragma unroll
  for (int c = 0; c < 2; c++){
    int co = co2 * 2 + c;
    float a = b1[co] + sp[t0 * 161 + co] + sp[t1 * 161 + 40 + co]
            + sp[t2 * 161 + 80 + co] + sp[t3 * 161 + 120 + co];
    h1[(size_t)(b * NC1 + co) * L1P + p] = relu_(a);
  }
}

// ---- conv2: 40->80, K=8; register-chunk prefetch of 8 input channels ----
__global__ __launch_bounds__(256) void k_conv2(const float* __restrict__ x,
                        const float* __restrict__ w, const float* __restrict__ bias,
                        float* __restrict__ y){
  int b = blockIdx.x / NC2, co = blockIdx.x % NC2;
  __shared__ float4 ws4[NC1 * 2];     // 40ci x 8k
  const float4* wg = (const float4*)(w + (size_t)co * (NC1 * 8));
  for (int k = threadIdx.x; k < NC1 * 2; k += 256) ws4[k] = wg[k];
  __syncthreads();
  int p0 = threadIdx.x * 4;
  if (p0 >= L2O) return;
  float bv = bias[co];
  float a0 = bv, a1 = bv, a2 = bv, a3 = bv;
  const float* xb = x + (size_t)b * NC1 * L1P;
  for (int c8 = 0; c8 < NC1; c8 += 8){
    float4 xv[8][3];
    #pragma unroll
    for (int u = 0; u < 8; u++){
      const float4* xr = (const float4*)(xb + (size_t)(c8 + u) * L1P + p0);
      xv[u][0] = xr[0]; xv[u][1] = xr[1]; xv[u][2] = xr[2];
    }
    #pragma unroll
    for (int u = 0; u < 8; u++){
      float xs[12];
      xs[0]=xv[u][0].x; xs[1]=xv[u][0].y; xs[2]=xv[u][0].z; xs[3]=xv[u][0].w;
      xs[4]=xv[u][1].x; xs[5]=xv[u][1].y; xs[6]=xv[u][1].z; xs[7]=xv[u][1].w;
      xs[8]=xv[u][2].x; xs[9]=xv[u][2].y; xs[10]=xv[u][2].z; xs[11]=xv[u][2].w;
      float4 w0 = ws4[(c8 + u) * 2], w1v = ws4[(c8 + u) * 2 + 1];
      float wk[8] = {w0.x,w0.y,w0.z,w0.w, w1v.x,w1v.y,w1v.z,w1v.w};
      #pragma unroll
      for (int k = 0; k < 8; k++){
        a0 = fmaf(xs[k],     wk[k], a0);
        a1 = fmaf(xs[k + 1], wk[k], a1);
        a2 = fmaf(xs[k + 2], wk[k], a2);
        a3 = fmaf(xs[k + 3], wk[k], a3);
      }
    }
  }
  float* yr = y + (size_t)(b * NC2 + co) * L2P + p0;
  if (p0 + 3 < L2O){
    float4 o; o.x = relu_(a0); o.y = relu_(a1); o.z = relu_(a2); o.w = relu_(a3);
    *(float4*)yr = o;
  } else {
    float aa[4] = {a0, a1, a2, a3};
    for (int j = 0; j < 4; j++) if (p0 + j < L2O) yr[j] = relu_(aa[j]);
  }
}

// ---- conv3: 80->160, K=12; register-chunk prefetch of 8 input channels ----
__global__ __launch_bounds__(256) void k_conv3(const float* __restrict__ x,
                        const float* __restrict__ w, const float* __restrict__ bias,
                        float* __restrict__ y){
  int b = blockIdx.x / NC3, co = blockIdx.x % NC3;
  __shared__ float4 ws4[NC2 * 3];     // 80ci x 12k
  const float4* wg = (const float4*)(w + (size_t)co * (NC2 * 12));
  for (int k = threadIdx.x; k < NC2 * 3; k += 256) ws4[k] = wg[k];
  __syncthreads();
  int p0 = threadIdx.x * 4;
  if (p0 >= L3O) return;
  float bv = bias[co];
  float a0 = bv, a1 = bv, a2 = bv, a3 = bv;
  const float* xb = x + (size_t)b * NC2 * L2P;
  for (int c8 = 0; c8 < NC2; c8 += 8){
    float4 xv[8][4];
    #pragma unroll
    for (int u = 0; u < 8; u++){
      const float4* xr = (const float4*)(xb + (size_t)(c8 + u) * L2P + p0);
      xv[u][0] = xr[0]; xv[u][1] = xr[1]; xv[u][2] = xr[2]; xv[u][3] = xr[3];
    }
    #pragma unroll
    for (int u = 0; u < 8; u++){
      float xs[16];
      xs[0]=xv[u][0].x;  xs[1]=xv[u][0].y;  xs[2]=xv[u][0].z;  xs[3]=xv[u][0].w;
      xs[4]=xv[u][1].x;  xs[5]=xv[u][1].y;  xs[6]=xv[u][1].z;  xs[7]=xv[u][1].w;
      xs[8]=xv[u][2].x;  xs[9]=xv[u][2].y;  xs[10]=xv[u][2].z; xs[11]=xv[u][2].w;
      xs[12]=xv[u][3].x; xs[13]=xv[u][3].y; xs[14]=xv[u][3].z; xs[15]=xv[u][3].w;
      float4 w0 = ws4[(c8 + u) * 3], w1v = ws4[(c8 + u) * 3 + 1], w2v = ws4[(c8 + u) * 3 + 2];
      float wk[12] = {w0.x,w0.y,w0.z,w0.w, w1v.x,w1v.y,w1v.z,w1v.w,
                      w2v.x,w2v.y,w2v.z,w2v.w};
      #pragma unroll
      for (int k = 0; k < 12; k++){
        a0 = fmaf(xs[k],     wk[k], a0);
        a1 = fmaf(xs[k + 1], wk[k], a1);
        a2 = fmaf(xs[k + 2], wk[k], a2);
        a3 = fmaf(xs[k + 3], wk[k], a3);
      }
    }
  }
  float* yr = y + (size_t)(b * NC3 + co) * L3P + p0;
  if (p0 + 3 < L3O){
    float4 o; o.x = relu_(a0); o.y = relu_(a1); o.z = relu_(a2); o.w = relu_(a3);
    *(float4*)yr = o;
  } else {
    float aa[4] = {a0, a1, a2, a3};
    for (int j = 0; j < 4; j++) if (p0 + j < L3O) yr[j] = relu_(aa[j]);
  }
}

// ---- fused drug-att + protein-att (+ enc init) ----
__global__ __launch_bounds__(256) void k_dpatt(const float* __restrict__ drug,
                        const int* __restrict__ natoms, const int* __restrict__ prot,
                        const float* __restrict__ pconv,
                        const float* __restrict__ Wd, const float* __restrict__ bd,
                        const float* __restrict__ Wp, const float* __restrict__ bp,
                        float* __restrict__ dattT, float* __restrict__ pattT,
                        unsigned* __restrict__ enc){
  int blk = blockIdx.x;
  if (blk == 0){
    for (int k = threadIdx.x; k < 2 * BB * NC3; k += 256) enc[k] = 0u;
  }
  if (blk < 80){
    int b = blk / 20, c0 = (blk % 20) * 8;
    int i = threadIdx.x;
    if (i >= DL) return;
    const float4* xr = (const float4*)(drug + ((size_t)b * DL + i) * NC3);
    float4 a[8];
    #pragma unroll
    for (int cc = 0; cc < 8; cc++) a[cc] = make_float4(0.f, 0.f, 0.f, 0.f);
    for (int k4 = 0; k4 < 40; k4++){
      float4 xv = xr[k4];
      #pragma unroll
      for (int cc = 0; cc < 8; cc++){
        float4 wv = ((const float4*)(Wd + (size_t)(c0 + cc) * NC3))[k4];
        a[cc].x = fmaf(xv.x, wv.x, a[cc].x);
        a[cc].y = fmaf(xv.y, wv.y, a[cc].y);
        a[cc].z = fmaf(xv.z, wv.z, a[cc].z);
        a[cc].w = fmaf(xv.w, wv.w, a[cc].w);
      }
    }
    bool act = i < natoms[b];
    #pragma unroll
    for (int cc = 0; cc < 8; cc++){
      float r = act ? (a[cc].x + a[cc].y + a[cc].z + a[cc].w + bd[c0 + cc]) : 0.f;
      dattT[(size_t)(b * NC3 + c0 + cc) * DLP + i] = r;
    }
  } else {
    int t = blk - 80;
    int b = t / 80, r = t % 80, jt = r / 20, c0 = (r % 20) * 8;
    int j = jt * 256 + threadIdx.x;
    if (j >= L3O) return;
    float acc[8];
    #pragma unroll
    for (int cc = 0; cc < 8; cc++) acc[cc] = bp[c0 + cc];
    const float* xc = pconv + (size_t)b * NC3 * L3P + j;
    const float* wr = Wp + (size_t)c0 * NC3;
    for (int cb = 0; cb < NC3; cb += 32){
      float xv[32];
      #pragma unroll
      for (int u = 0; u < 32; u++) xv[u] = xc[(size_t)(cb + u) * L3P];
      #pragma unroll
      for (int u = 0; u < 32; u++){
        #pragma unroll
        for (int cc = 0; cc < 8; cc++)
          acc[cc] = fmaf(xv[u], wr[(size_t)cc * NC3 + cb + u], acc[cc]);
      }
    }
    bool act = prot[b * PL + j] > 0;
    #pragma unroll
    for (int cc = 0; cc < 8; cc++)
      pattT[(size_t)(b * NC3 + c0 + cc) * PLP + j] = act ? acc[cc] : 0.f;
  }
}

// ---- means of relu(da_i + pa_j): block=(b,c), float4 LDS ----
__global__ __launch_bounds__(256) void k_means(const float* __restrict__ dattT,
                        const float* __restrict__ pattT,
                        float* __restrict__ cmeanT, float* __restrict__ pmeanT){
  __shared__ float4 sda4[DLP / 4];    // 38
  __shared__ float4 spa4[PLP / 4];    // 246
  float* sda = (float*)sda4;
  float* spa = (float*)spa4;
  int b = blockIdx.x / NC3, c = blockIdx.x % NC3;
  int tid = threadIdx.x;
  const float4* dr = (const float4*)(dattT + (size_t)(b * NC3 + c) * DLP);
  const float4* pr = (const float4*)(pattT + (size_t)(b * NC3 + c) * PLP);
  if (tid < DLP / 4) sda4[tid] = dr[tid];
  if (tid < PLP / 4) spa4[tid] = pr[tid];   // tail beyond L3O is garbage; not used
  __syncthreads();
  if (tid < DL){
    float v = sda[tid];
    float s0 = 0.f, s1 = 0.f, s2 = 0.f, s3 = 0.f;
    for (int j4 = 0; j4 < 244; j4++){       // 976 elements
      float4 p = spa4[j4];
      s0 += relu_(v + p.x); s1 += relu_(v + p.y);
      s2 += relu_(v + p.z); s3 += relu_(v + p.w);
    }
    s0 += relu_(v + spa[976]) + relu_(v + spa[977]) + relu_(v + spa[978]);
    cmeanT[(size_t)(b * NC3 + c) * DLP + tid] = (s0 + s1 + s2 + s3) * (1.f / L3O);
  }
  for (int j = tid; j < L3O; j += 256){
    float v = spa[j];
    float s0 = 0.f, s1 = 0.f, s2 = 0.f, s3 = 0.f;
    for (int i4 = 0; i4 < 37; i4++){        // 148 elements
      float4 d = sda4[i4];
      s0 += relu_(v + d.x); s1 += relu_(v + d.y);
      s2 += relu_(v + d.z); s3 += relu_(v + d.w);
    }
    s0 += relu_(v + sda[148]) + relu_(v + sda[149]);
    pmeanT[(size_t)(b * NC3 + c) * PLP + j] = (s0 + s1 + s2 + s3) * (1.f / DL);
  }
}

// ---- fused gates + max-pool ----
__global__ __launch_bounds__(256) void k_atte(const float* __restrict__ cmeanT,
                        const float* __restrict__ pmeanT, const float* __restrict__ Watt,
                        const float* __restrict__ batt, const float* __restrict__ drug,
                        const float* __restrict__ pconv, unsigned* __restrict__ enc){
  __shared__ float sred[4][8];
  int blk = blockIdx.x;
  float m[8];
  #pragma unroll
  for (int cc = 0; cc < 8; cc++) m[cc] = NINF;
  int encbase;
  if (blk < 80){
    int b = blk / 20, c0 = (blk % 20) * 8;
    encbase = b * NC3 + c0;
    int i = threadIdx.x;
    if (i < DL){
      float acc[8];
      #pragma unroll
      for (int cc = 0; cc < 8; cc++) acc[cc] = batt[c0 + cc];
      const float* xc = cmeanT + (size_t)b * NC3 * DLP + i;
      const float* wr = Watt + (size_t)c0 * NC3;
      for (int cb = 0; cb < NC3; cb += 32){
        float xv[32];
        #pragma unroll
        for (int u = 0; u < 32; u++) xv[u] = xc[(size_t)(cb + u) * DLP];
        #pragma unroll
        for (int u = 0; u < 32; u++){
          #pragma unroll
          for (int cc = 0; cc < 8; cc++)
            acc[cc] = fmaf(xv[u], wr[(size_t)cc * NC3 + cb + u], acc[cc]);
        }
      }
      const float* gr = drug + ((size_t)b * DL + i) * NC3 + c0;
      #pragma unroll
      for (int cc = 0; cc < 8; cc++){
        float atte = 1.f / (1.f + expf(-acc[cc]));
        m[cc] = gr[cc] * (0.5f + atte);
      }
    }
  } else {
    int t = blk - 80;
    int b = t / 80, r = t % 80, jt = r / 20, c0 = (r % 20) * 8;
    encbase = BB * NC3 + b * NC3 + c0;
    int j = jt * 256 + threadIdx.x;
    if (j < L3O){
      float acc[8];
      #pragma unroll
      for (int cc = 0; cc < 8; cc++) acc[cc] = batt[c0 + cc];
      const float* xc = pmeanT + (size_t)b * NC3 * PLP + j;
      const float* wr = Watt + (size_t)c0 * NC3;
      for (int cb = 0; cb < NC3; cb += 32){
        float xv[32];
        #pragma unroll
        for (int u = 0; u < 32; u++) xv[u] = xc[(size_t)(cb + u) * PLP];
        #pragma unroll
        for (int u = 0; u < 32; u++){
          #pragma unroll
          for (int cc = 0; cc < 8; cc++)
            acc[cc] = fmaf(xv[u], wr[(size_t)cc * NC3 + cb + u], acc[cc]);
        }
      }
      const float* gr = pconv + (size_t)b * NC3 * L3P + j;
      #pragma unroll
      for (int cc = 0; cc < 8; cc++){
        float atte = 1.f / (1.f + expf(-acc[cc]));
        m[cc] = gr[(size_t)(c0 + cc) * L3P] * (0.5f + atte);
      }
    }
  }
  int wave = threadIdx.x >> 6, lane = threadIdx.x & 63;
  #pragma unroll
  for (int cc = 0; cc < 8; cc++){
    float v = m[cc];
    for (int off = 1; off < 64; off <<= 1) v = fmaxf(v, __shfl_xor(v, off, 64));
    if (lane == 0) sred[wave][cc] = v;
  }
  __syncthreads();
  if (threadIdx.x < 8){
    float v = fmaxf(fmaxf(sred[0][threadIdx.x], sred[1][threadIdx.x]),
                    fmaxf(sred[2][threadIdx.x], sred[3][threadIdx.x]));
    atomicMax(&enc[encbase + threadIdx.x], fenc(v));
  }
}

// ---- MLP 1: 320 -> 1024 ----
__global__ __launch_bounds__(256) void k_mlp1(const unsigned* __restrict__ enc,
                        const float* __restrict__ W1, const float* __restrict__ bf1,
                        float* __restrict__ f1){
  int b = blockIdx.x >> 4;
  int o = (blockIdx.x & 15) * 64 + (threadIdx.x >> 2);
  int q = threadIdx.x & 3;
  int k0 = q * 80;
  const float4* wr = (const float4*)(W1 + (size_t)o * 320 + k0);
  float4 a = make_float4(0.f, 0.f, 0.f, 0.f);
  for (int mI = 0; mI < 20; mI++){
    float4 wv = wr[mI];
    int k = k0 + mI * 4;
    const unsigned* e = (k < 160) ? (enc + b * NC3 + k) : (enc + BB * NC3 + b * NC3 + (k - 160));
    a.x = fmaf(fdec(e[0]), wv.x, a.x);
    a.y = fmaf(fdec(e[1]), wv.y, a.y);
    a.z = fmaf(fdec(e[2]), wv.z, a.z);
    a.w = fmaf(fdec(e[3]), wv.w, a.w);
  }
  float r = a.x + a.y + a.z + a.w;
  r += __shfl_xor(r, 1, 64);
  r += __shfl_xor(r, 2, 64);
  if (q == 0) f1[b * 1024 + o] = lrelu_(r + bf1[o]);
}

// ---- MLP 2: 1024 -> 1024 ----
__global__ __launch_bounds__(256) void k_mlp2(const float* __restrict__ x,
                        const float* __restrict__ W, const float* __restrict__ bias,
                        float* __restrict__ y){
  int b = blockIdx.x >> 4;
  int o = (blockIdx.x & 15) * 64 + (threadIdx.x >> 2);
  int q = threadIdx.x & 3;
  int k0 = q * 256;
  const float4* wr = (const float4*)(W + (size_t)o * 1024 + k0);
  const float4* xr = (const float4*)(x + b * 1024 + k0);
  float4 a = make_float4(0.f, 0.f, 0.f, 0.f);
  #pragma unroll 4
  for (int mI = 0; mI < 64; mI++){
    float4 wv = wr[mI], xv = xr[mI];
    a.x = fmaf(xv.x, wv.x, a.x);
    a.y = fmaf(xv.y, wv.y, a.y);
    a.z = fmaf(xv.z, wv.z, a.z);
    a.w = fmaf(xv.w, wv.w, a.w);
  }
  float r = a.x + a.y + a.z + a.w;
  r += __shfl_xor(r, 1, 64);
  r += __shfl_xor(r, 2, 64);
  if (q == 0) y[b * 1024 + o] = lrelu_(r + bias[o]);
}

// ---- MLP 3: 1024 -> 512 ----
__global__ __launch_bounds__(256) void k_mlp3(const float* __restrict__ x,
                        const float* __restrict__ W, const float* __restrict__ bias,
                        float* __restrict__ y){
  int b = blockIdx.x >> 3;
  int o = (blockIdx.x & 7) * 64 + (threadIdx.x >> 2);
  int q = threadIdx.x & 3;
  int k0 = q * 256;
  const float4* wr = (const float4*)(W + (size_t)o * 1024 + k0);
  const float4* xr = (const float4*)(x + b * 1024 + k0);
  float4 a = make_float4(0.f, 0.f, 0.f, 0.f);
  #pragma unroll 4
  for (int mI = 0; mI < 64; mI++){
    float4 wv = wr[mI], xv = xr[mI];
    a.x = fmaf(xv.x, wv.x, a.x);
    a.y = fmaf(xv.y, wv.y, a.y);
    a.z = fmaf(xv.z, wv.z, a.z);
    a.w = fmaf(xv.w, wv.w, a.w);
  }
  float r = a.x + a.y + a.z + a.w;
  r += __shfl_xor(r, 1, 64);
  r += __shfl_xor(r, 2, 64);
  if (q == 0) y[b * 512 + o] = lrelu_(r + bias[o]);
}

// ---- MLP out: 512 -> 2 ----
__global__ void k_mlp4(const float* __restrict__ f3, const float* __restrict__ Wo,
                       const float* __restrict__ bo, float* __restrict__ out){
  int tid = threadIdx.x;
  int g = tid >> 5, lane = tid & 31;
  int b = g >> 1, o = g & 1;
  const float4* xr = (const float4*)(f3 + b * 512);
  const float4* wr = (const float4*)(Wo + o * 512);
  float4 a = make_float4(0.f, 0.f, 0.f, 0.f);
  #pragma unroll
  for (int mI = 0; mI < 4; mI++){
    int k4 = lane + mI * 32;
    float4 xv = xr[k4], wv = wr[k4];
    a.x = fmaf(xv.x, wv.x, a.x);
    a.y = fmaf(xv.y, wv.y, a.y);
    a.z = fmaf(xv.z, wv.z, a.z);
    a.w = fmaf(xv.w, wv.w, a.w);
  }
  float r = a.x + a.y + a.z + a.w;
  for (int off = 16; off; off >>= 1) r += __shfl_xor(r, off, 64);
  if (lane == 0) out[b * 2 + o] = r + bo[o];
}

extern "C" void kernel_launch(void* const* d_in, const int* in_sizes, int n_in,
                              void* d_out, int out_size, void* d_ws, size_t ws_size,
                              hipStream_t stream) {
  const float* drug  = (const float*)d_in[0];
  const int*   natoms= (const int*)d_in[1];
  const int*   prot  = (const int*)d_in[2];
  const float* emb   = (const float*)d_in[3];
  const float* w1    = (const float*)d_in[4];
  const float* b1    = (const float*)d_in[5];
  const float* w2    = (const float*)d_in[6];
  const float* b2    = (const float*)d_in[7];
  const float* w3    = (const float*)d_in[8];
  const float* b3    = (const float*)d_in[9];
  const float* Wd    = (const float*)d_in[10];
  const float* bd    = (const float*)d_in[11];
  const float* Wp    = (const float*)d_in[12];
  const float* bp    = (const float*)d_in[13];
  const float* Watt  = (const float*)d_in[14];
  const float* batt  = (const float*)d_in[15];
  const float* W1    = (const float*)d_in[16];
  const float* bf1   = (const float*)d_in[17];
  const float* W2    = (const float*)d_in[18];
  const float* bf2   = (const float*)d_in[19];
  const float* W3    = (const float*)d_in[20];
  const float* bf3   = (const float*)d_in[21];
  const float* Wo    = (const float*)d_in[22];
  const float* bo    = (const float*)d_in[23];
  float* out = (float*)d_out;

  float* ws = (float*)d_ws;
  float* h1     = ws;                       // 160000 (reused later)
  float* cmeanT = ws;                       // 97280
  float* f1     = ws + 97280;               // 4096
  float* f2     = ws + 101376;              // 4096
  float* f3     = ws + 105472;              // 2048
  float* h2     = ws + 160000;              // 317440
  float* pconv  = ws + 477440;              // 627200
  float* dattT  = ws + 1104640;             // 97280
  float* pattT  = ws + 1201920;             // 629760
  float* pmeanT = ws + 1831680;             // 629760
  unsigned* enc = (unsigned*)(ws + 2461440);// 1280 u32
  float* projG  = ws + 2461760;             // 4186

  k_proj <<<17, 256, 0, stream>>>(emb, w1, projG);
  k_conv1<<<BB * 80, 256, 0, stream>>>(prot, projG, b1, h1);
  k_conv2<<<BB * NC2, 256, 0, stream>>>(h1, w2, b2, h2);
  k_conv3<<<BB * NC3, 256, 0, stream>>>(h2, w3, b3, pconv);
  k_dpatt<<<400, 256, 0, stream>>>(drug, natoms, prot, pconv, Wd, bd, Wp, bp,
                                   dattT, pattT, enc);
  k_means<<<BB * NC3, 256, 0, stream>>>(dattT, pattT, cmeanT, pmeanT);
  k_atte <<<400, 256, 0, stream>>>(cmeanT, pmeanT, Watt, batt, drug, pconv, enc);
  k_mlp1 <<<64, 256, 0, stream>>>(enc, W1, bf1, f1);
  k_mlp2 <<<64, 256, 0, stream>>>(f1, W2, bf2, f2);
  k_mlp3 <<<32, 256, 0, stream>>>(f2, W3, bf3, f3);
  k_mlp4 <<<1, 256, 0, stream>>>(f3, Wo, bo, out);
}

// Round 4
// 184.429 us; speedup vs baseline: 1.3897x; 1.3897x over previous
//
#include <hip/hip_runtime.h>
#include <math.h>

#define BB 4
#define DL 150
#define PL 1000
#define CD 64
#define NC1 40
#define NC2 80
#define NC3 160
#define L1O 997
#define L2O 990
#define L3O 979
#define L1P 1000
#define L2P 992
#define L3P 980
#define DLP 152
#define PLP 984
#define NINF (-1e30f)

__device__ __forceinline__ float relu_(float x){ return fmaxf(x, 0.f); }
__device__ __forceinline__ float lrelu_(float x){ return x > 0.f ? x : 0.01f * x; }

__device__ __forceinline__ unsigned fenc(float x){
  unsigned u = __float_as_uint(x);
  return (u & 0x80000000u) ? ~u : (u | 0x80000000u);
}
__device__ __forceinline__ float fdec(unsigned u){
  return __uint_as_float((u & 0x80000000u) ? (u & 0x7fffffffu) : ~u);
}

// ---- proj table: proj[tok][k][co] = sum_ci emb[tok][ci] * w1[co][ci][k] ----
__global__ void k_proj(const float* __restrict__ emb, const float* __restrict__ w1,
                       float* __restrict__ projG){
  int e = blockIdx.x * 256 + threadIdx.x;
  if (e >= 26 * 160) return;
  int tok = e / 160, rem = e % 160, k = rem / 40, co = rem % 40;
  float a = 0.f;
  const float* er = emb + tok * CD;
  const float* wr = w1 + co * (CD * 4) + k;
  #pragma unroll 8
  for (int ci = 0; ci < CD; ci++) a = fmaf(er[ci], wr[ci * 4], a);
  projG[tok * 161 + k * 40 + co] = a;
}

// ---- conv1 apply ----
__global__ __launch_bounds__(256) void k_conv1(const int* __restrict__ prot,
                        const float* __restrict__ projG, const float* __restrict__ b1,
                        float* __restrict__ h1){
  __shared__ float sp[26 * 161];
  int b = blockIdx.x / 80;
  int t = (blockIdx.x % 80) * 256 + threadIdx.x;
  for (int k = threadIdx.x; k < 26 * 161; k += 256) sp[k] = projG[k];
  __syncthreads();
  int p = t & 1023, co2 = t >> 10;
  if (p >= L1O) return;
  const int* pr = prot + b * PL + p;
  int t0 = pr[0], t1 = pr[1], t2 = pr[2], t3 = pr[3];
  #pragma unroll
  for (int c = 0; c < 2; c++){
    int co = co2 * 2 + c;
    float a = b1[co] + sp[t0 * 161 + co] + sp[t1 * 161 + 40 + co]
            + sp[t2 * 161 + 80 + co] + sp[t3 * 161 + 120 + co];
    h1[(size_t)(b * NC1 + co) * L1P + p] = relu_(a);
  }
}

// ---- conv2: 40->80, K=8. LDS-tiled: 16co x 64p per block, X+W staged once ----
#define C2_XW 76
#define C2_WP 324
__global__ __launch_bounds__(256) void k_conv2(const float* __restrict__ x,
                        const float* __restrict__ w, const float* __restrict__ bias,
                        float* __restrict__ y){
  __shared__ float xs_lds[NC1 * C2_XW];       // 40*76*4 = 12.2KB
  __shared__ float w_lds[16 * C2_WP];         // 16*324*4 = 20.7KB
  int blk = blockIdx.x;
  int b = blk / 80, r = blk % 80, cog = r / 16, pt = r % 16;
  int co0 = cog * 16, pblk = pt * 64;
  int tid = threadIdx.x;
  const float* xb = x + (size_t)b * NC1 * L1P + pblk;
  for (int i = tid; i < 760; i += 256){       // 40 rows x 19 float4
    int row = i / 19, c4 = i % 19;
    *(float4*)(&xs_lds[row * C2_XW + c4 * 4]) =
        *(const float4*)(xb + (size_t)row * L1P + c4 * 4);
  }
  const float* wb = w + (size_t)co0 * 320;
  for (int i = tid; i < 1280; i += 256){      // 16 co x 80 float4
    int co = i / 80, c4 = i % 80;
    *(float4*)(&w_lds[co * C2_WP + c4 * 4]) =
        *(const float4*)(wb + (size_t)co * 320 + c4 * 4);
  }
  __syncthreads();
  int co_l = tid >> 4, pg = tid & 15;
  int p0 = pg * 4;
  float acc[4] = {0.f, 0.f, 0.f, 0.f};
  const float* wc = &w_lds[co_l * C2_WP];
  #pragma unroll 4
  for (int ci = 0; ci < NC1; ci++){
    const float* xrow = &xs_lds[ci * C2_XW + p0];
    float xs[12];
    *(float4*)(&xs[0]) = *(const float4*)(xrow);
    *(float4*)(&xs[4]) = *(const float4*)(xrow + 4);
    *(float4*)(&xs[8]) = *(const float4*)(xrow + 8);
    float wk[8];
    *(float4*)(&wk[0]) = *(const float4*)(wc + ci * 8);
    *(float4*)(&wk[4]) = *(const float4*)(wc + ci * 8 + 4);
    #pragma unroll
    for (int k = 0; k < 8; k++){
      #pragma unroll
      for (int pp = 0; pp < 4; pp++)
        acc[pp] = fmaf(xs[pp + k], wk[k], acc[pp]);
    }
  }
  int co = co0 + co_l;
  float bv = bias[co];
  int pbase = pblk + p0;
  float* yr = y + (size_t)(b * NC2 + co) * L2P + pbase;
  if (pbase + 3 < L2O){
    float4 o; o.x = relu_(acc[0] + bv); o.y = relu_(acc[1] + bv);
    o.z = relu_(acc[2] + bv); o.w = relu_(acc[3] + bv);
    *(float4*)yr = o;
  } else {
    #pragma unroll
    for (int pp = 0; pp < 4; pp++)
      if (pbase + pp < L2O) yr[pp] = relu_(acc[pp] + bv);
  }
}

// ---- conv3: 80->160, K=12. LDS-tiled: 32co x 64p, W double-buffered by 16-ci chunks ----
#define C3_XW 76
#define C3_WP 196
__global__ __launch_bounds__(256) void k_conv3(const float* __restrict__ x,
                        const float* __restrict__ w, const float* __restrict__ bias,
                        float* __restrict__ y){
  __shared__ float xs_lds[NC2 * C3_XW];       // 80*76*4 = 24.3KB
  __shared__ float w_lds[2][32 * C3_WP];      // 2*32*196*4 = 50.2KB
  int blk = blockIdx.x;
  int b = blk / 80, r = blk % 80, cog = r / 16, pt = r % 16;
  int co0 = cog * 32, pblk = pt * 64;
  int tid = threadIdx.x;
  const float* xb = x + (size_t)b * NC2 * L2P + pblk;
  for (int i = tid; i < 1520; i += 256){      // 80 rows x 19 float4
    int row = i / 19, c4 = i % 19;
    *(float4*)(&xs_lds[row * C3_XW + c4 * 4]) =
        *(const float4*)(xb + (size_t)row * L2P + c4 * 4);
  }
  {
    const float* wb = w + (size_t)co0 * 960;
    for (int i = tid; i < 1536; i += 256){    // 32 co x 48 float4 (chunk 0)
      int co = i / 48, c4 = i % 48;
      *(float4*)(&w_lds[0][co * C3_WP + c4 * 4]) =
          *(const float4*)(wb + (size_t)co * 960 + c4 * 4);
    }
  }
  __syncthreads();
  int co_l = tid >> 3, pg = tid & 7;
  int p0 = pg * 8;
  float acc[8] = {0.f,0.f,0.f,0.f,0.f,0.f,0.f,0.f};
  int pfco = tid / 48, pfc4 = tid % 48;       // reused staging decomposition
  for (int ch = 0; ch < 5; ch++){
    float4 pf0, pf1, pf2, pf3, pf4, pf5;
    if (ch < 4){
      const float* wb = w + (size_t)co0 * 960 + (ch + 1) * 192;
      const float* s0 = wb + (size_t)((tid          ) / 48) * 960 + ((tid          ) % 48) * 4;
      const float* s1 = wb + (size_t)((tid + 256    ) / 48) * 960 + ((tid + 256    ) % 48) * 4;
      const float* s2 = wb + (size_t)((tid + 512    ) / 48) * 960 + ((tid + 512    ) % 48) * 4;
      const float* s3 = wb + (size_t)((tid + 768    ) / 48) * 960 + ((tid + 768    ) % 48) * 4;
      const float* s4 = wb + (size_t)((tid + 1024   ) / 48) * 960 + ((tid + 1024   ) % 48) * 4;
      const float* s5 = wb + (size_t)((tid + 1280   ) / 48) * 960 + ((tid + 1280   ) % 48) * 4;
      pf0 = *(const float4*)s0; pf1 = *(const float4*)s1; pf2 = *(const float4*)s2;
      pf3 = *(const float4*)s3; pf4 = *(const float4*)s4; pf5 = *(const float4*)s5;
    }
    const float* wc = &w_lds[ch & 1][co_l * C3_WP];
    #pragma unroll 2
    for (int rci = 0; rci < 16; rci++){
      const float* xrow = &xs_lds[(ch * 16 + rci) * C3_XW + p0];
      float xs[20];
      *(float4*)(&xs[0])  = *(const float4*)(xrow);
      *(float4*)(&xs[4])  = *(const float4*)(xrow + 4);
      *(float4*)(&xs[8])  = *(const float4*)(xrow + 8);
      *(float4*)(&xs[12]) = *(const float4*)(xrow + 12);
      *(float4*)(&xs[16]) = *(const float4*)(xrow + 16);
      float wk[12];
      *(float4*)(&wk[0]) = *(const float4*)(wc + rci * 12);
      *(float4*)(&wk[4]) = *(const float4*)(wc + rci * 12 + 4);
      *(float4*)(&wk[8]) = *(const float4*)(wc + rci * 12 + 8);
      #pragma unroll
      for (int k = 0; k < 12; k++){
        #pragma unroll
        for (int pp = 0; pp < 8; pp++)
          acc[pp] = fmaf(xs[pp + k], wk[k], acc[pp]);
      }
    }
    if (ch < 4){
      __syncthreads();
      float* dbase = w_lds[(ch + 1) & 1];
      *(float4*)(&dbase[((tid          ) / 48) * C3_WP + ((tid          ) % 48) * 4]) = pf0;
      *(float4*)(&dbase[((tid + 256    ) / 48) * C3_WP + ((tid + 256    ) % 48) * 4]) = pf1;
      *(float4*)(&dbase[((tid + 512    ) / 48) * C3_WP + ((tid + 512    ) % 48) * 4]) = pf2;
      *(float4*)(&dbase[((tid + 768    ) / 48) * C3_WP + ((tid + 768    ) % 48) * 4]) = pf3;
      *(float4*)(&dbase[((tid + 1024   ) / 48) * C3_WP + ((tid + 1024   ) % 48) * 4]) = pf4;
      *(float4*)(&dbase[((tid + 1280   ) / 48) * C3_WP + ((tid + 1280   ) % 48) * 4]) = pf5;
      __syncthreads();
    }
  }
  (void)pfco; (void)pfc4;
  int co = co0 + co_l;
  float bv = bias[co];
  int pbase = pblk + p0;
  float* yr = y + (size_t)(b * NC3 + co) * L3P + pbase;
  if (pbase + 7 < L3O){
    float4 o0, o1;
    o0.x = relu_(acc[0] + bv); o0.y = relu_(acc[1] + bv);
    o0.z = relu_(acc[2] + bv); o0.w = relu_(acc[3] + bv);
    o1.x = relu_(acc[4] + bv); o1.y = relu_(acc[5] + bv);
    o1.z = relu_(acc[6] + bv); o1.w = relu_(acc[7] + bv);
    *(float4*)yr = o0; *(float4*)(yr + 4) = o1;
  } else {
    #pragma unroll
    for (int pp = 0; pp < 8; pp++)
      if (pbase + pp < L3O) yr[pp] = relu_(acc[pp] + bv);
  }
}

// ---- fused drug-att + protein-att (+ enc init) ----
__global__ __launch_bounds__(256) void k_dpatt(const float* __restrict__ drug,
                        const int* __restrict__ natoms, const int* __restrict__ prot,
                        const float* __restrict__ pconv,
                        const float* __restrict__ Wd, const float* __restrict__ bd,
                        const float* __restrict__ Wp, const float* __restrict__ bp,
                        float* __restrict__ dattT, float* __restrict__ pattT,
                        unsigned* __restrict__ enc){
  int blk = blockIdx.x;
  if (blk == 0){
    for (int k = threadIdx.x; k < 2 * BB * NC3; k += 256) enc[k] = 0u;
  }
  if (blk < 80){
    int b = blk / 20, c0 = (blk % 20) * 8;
    int i = threadIdx.x;
    if (i >= DL) return;
    const float4* xr = (const float4*)(drug + ((size_t)b * DL + i) * NC3);
    float4 a[8];
    #pragma unroll
    for (int cc = 0; cc < 8; cc++) a[cc] = make_float4(0.f, 0.f, 0.f, 0.f);
    for (int k4 = 0; k4 < 40; k4++){
      float4 xv = xr[k4];
      #pragma unroll
      for (int cc = 0; cc < 8; cc++){
        float4 wv = ((const float4*)(Wd + (size_t)(c0 + cc) * NC3))[k4];
        a[cc].x = fmaf(xv.x, wv.x, a[cc].x);
        a[cc].y = fmaf(xv.y, wv.y, a[cc].y);
        a[cc].z = fmaf(xv.z, wv.z, a[cc].z);
        a[cc].w = fmaf(xv.w, wv.w, a[cc].w);
      }
    }
    bool act = i < natoms[b];
    #pragma unroll
    for (int cc = 0; cc < 8; cc++){
      float r = act ? (a[cc].x + a[cc].y + a[cc].z + a[cc].w + bd[c0 + cc]) : 0.f;
      dattT[(size_t)(b * NC3 + c0 + cc) * DLP + i] = r;
    }
  } else {
    int t = blk - 80;
    int b = t / 80, r = t % 80, jt = r / 20, c0 = (r % 20) * 8;
    int j = jt * 256 + threadIdx.x;
    if (j >= L3O) return;
    float acc[8];
    #pragma unroll
    for (int cc = 0; cc < 8; cc++) acc[cc] = bp[c0 + cc];
    const float* xc = pconv + (size_t)b * NC3 * L3P + j;
    const float* wr = Wp + (size_t)c0 * NC3;
    for (int cb = 0; cb < NC3; cb += 32){
      float xv[32];
      #pragma unroll
      for (int u = 0; u < 32; u++) xv[u] = xc[(size_t)(cb + u) * L3P];
      #pragma unroll
      for (int u = 0; u < 32; u++){
        #pragma unroll
        for (int cc = 0; cc < 8; cc++)
          acc[cc] = fmaf(xv[u], wr[(size_t)cc * NC3 + cb + u], acc[cc]);
      }
    }
    bool act = prot[b * PL + j] > 0;
    #pragma unroll
    for (int cc = 0; cc < 8; cc++)
      pattT[(size_t)(b * NC3 + c0 + cc) * PLP + j] = act ? acc[cc] : 0.f;
  }
}

// ---- means of relu(da_i + pa_j): block=(b,c), float4 LDS ----
__global__ __launch_bounds__(256) void k_means(const float* __restrict__ dattT,
                        const float* __restrict__ pattT,
                        float* __restrict__ cmeanT, float* __restrict__ pmeanT){
  __shared__ float4 sda4[DLP / 4];
  __shared__ float4 spa4[PLP / 4];
  float* sda = (float*)sda4;
  float* spa = (float*)spa4;
  int b = blockIdx.x / NC3, c = blockIdx.x % NC3;
  int tid = threadIdx.x;
  const float4* dr = (const float4*)(dattT + (size_t)(b * NC3 + c) * DLP);
  const float4* pr = (const float4*)(pattT + (size_t)(b * NC3 + c) * PLP);
  if (tid < DLP / 4) sda4[tid] = dr[tid];
  if (tid < PLP / 4) spa4[tid] = pr[tid];
  __syncthreads();
  if (tid < DL){
    float v = sda[tid];
    float s0 = 0.f, s1 = 0.f, s2 = 0.f, s3 = 0.f;
    for (int j4 = 0; j4 < 244; j4++){
      float4 p = spa4[j4];
      s0 += relu_(v + p.x); s1 += relu_(v + p.y);
      s2 += relu_(v + p.z); s3 += relu_(v + p.w);
    }
    s0 += relu_(v + spa[976]) + relu_(v + spa[977]) + relu_(v + spa[978]);
    cmeanT[(size_t)(b * NC3 + c) * DLP + tid] = (s0 + s1 + s2 + s3) * (1.f / L3O);
  }
  for (int j = tid; j < L3O; j += 256){
    float v = spa[j];
    float s0 = 0.f, s1 = 0.f, s2 = 0.f, s3 = 0.f;
    for (int i4 = 0; i4 < 37; i4++){
      float4 d = sda4[i4];
      s0 += relu_(v + d.x); s1 += relu_(v + d.y);
      s2 += relu_(v + d.z); s3 += relu_(v + d.w);
    }
    s0 += relu_(v + sda[148]) + relu_(v + sda[149]);
    pmeanT[(size_t)(b * NC3 + c) * PLP + j] = (s0 + s1 + s2 + s3) * (1.f / DL);
  }
}

// ---- fused gates + max-pool ----
__global__ __launch_bounds__(256) void k_atte(const float* __restrict__ cmeanT,
                        const float* __restrict__ pmeanT, const float* __restrict__ Watt,
                        const float* __restrict__ batt, const float* __restrict__ drug,
                        const float* __restrict__ pconv, unsigned* __restrict__ enc){
  __shared__ float sred[4][8];
  int blk = blockIdx.x;
  float m[8];
  #pragma unroll
  for (int cc = 0; cc < 8; cc++) m[cc] = NINF;
  int encbase;
  if (blk < 80){
    int b = blk / 20, c0 = (blk % 20) * 8;
    encbase = b * NC3 + c0;
    int i = threadIdx.x;
    if (i < DL){
      float acc[8];
      #pragma unroll
      for (int cc = 0; cc < 8; cc++) acc[cc] = batt[c0 + cc];
      const float* xc = cmeanT + (size_t)b * NC3 * DLP + i;
      const float* wr = Watt + (size_t)c0 * NC3;
      for (int cb = 0; cb < NC3; cb += 32){
        float xv[32];
        #pragma unroll
        for (int u = 0; u < 32; u++) xv[u] = xc[(size_t)(cb + u) * DLP];
        #pragma unroll
        for (int u = 0; u < 32; u++){
          #pragma unroll
          for (int cc = 0; cc < 8; cc++)
            acc[cc] = fmaf(xv[u], wr[(size_t)cc * NC3 + cb + u], acc[cc]);
        }
      }
      const float* gr = drug + ((size_t)b * DL + i) * NC3 + c0;
      #pragma unroll
      for (int cc = 0; cc < 8; cc++){
        float atte = 1.f / (1.f + expf(-acc[cc]));
        m[cc] = gr[cc] * (0.5f + atte);
      }
    }
  } else {
    int t = blk - 80;
    int b = t / 80, r = t % 80, jt = r / 20, c0 = (r % 20) * 8;
    encbase = BB * NC3 + b * NC3 + c0;
    int j = jt * 256 + threadIdx.x;
    if (j < L3O){
      float acc[8];
      #pragma unroll
      for (int cc = 0; cc < 8; cc++) acc[cc] = batt[c0 + cc];
      const float* xc = pmeanT + (size_t)b * NC3 * PLP + j;
      const float* wr = Watt + (size_t)c0 * NC3;
      for (int cb = 0; cb < NC3; cb += 32){
        float xv[32];
        #pragma unroll
        for (int u = 0; u < 32; u++) xv[u] = xc[(size_t)(cb + u) * PLP];
        #pragma unroll
        for (int u = 0; u < 32; u++){
          #pragma unroll
          for (int cc = 0; cc < 8; cc++)
            acc[cc] = fmaf(xv[u], wr[(size_t)cc * NC3 + cb + u], acc[cc]);
        }
      }
      const float* gr = pconv + (size_t)b * NC3 * L3P + j;
      #pragma unroll
      for (int cc = 0; cc < 8; cc++){
        float atte = 1.f / (1.f + expf(-acc[cc]));
        m[cc] = gr[(size_t)(c0 + cc) * L3P] * (0.5f + atte);
      }
    }
  }
  int wave = threadIdx.x >> 6, lane = threadIdx.x & 63;
  #pragma unroll
  for (int cc = 0; cc < 8; cc++){
    float v = m[cc];
    for (int off = 1; off < 64; off <<= 1) v = fmaxf(v, __shfl_xor(v, off, 64));
    if (lane == 0) sred[wave][cc] = v;
  }
  __syncthreads();
  if (threadIdx.x < 8){
    float v = fmaxf(fmaxf(sred[0][threadIdx.x], sred[1][threadIdx.x]),
                    fmaxf(sred[2][threadIdx.x], sred[3][threadIdx.x]));
    atomicMax(&enc[encbase + threadIdx.x], fenc(v));
  }
}

// ---- MLP 1: 320 -> 1024 ----
__global__ __launch_bounds__(256) void k_mlp1(const unsigned* __restrict__ enc,
                        const float* __restrict__ W1, const float* __restrict__ bf1,
                        float* __restrict__ f1){
  int b = blockIdx.x >> 4;
  int o = (blockIdx.x & 15) * 64 + (threadIdx.x >> 2);
  int q = threadIdx.x & 3;
  int k0 = q * 80;
  const float4* wr = (const float4*)(W1 + (size_t)o * 320 + k0);
  float4 a = make_float4(0.f, 0.f, 0.f, 0.f);
  for (int mI = 0; mI < 20; mI++){
    float4 wv = wr[mI];
    int k = k0 + mI * 4;
    const unsigned* e = (k < 160) ? (enc + b * NC3 + k) : (enc + BB * NC3 + b * NC3 + (k - 160));
    a.x = fmaf(fdec(e[0]), wv.x, a.x);
    a.y = fmaf(fdec(e[1]), wv.y, a.y);
    a.z = fmaf(fdec(e[2]), wv.z, a.z);
    a.w = fmaf(fdec(e[3]), wv.w, a.w);
  }
  float r = a.x + a.y + a.z + a.w;
  r += __shfl_xor(r, 1, 64);
  r += __shfl_xor(r, 2, 64);
  if (q == 0) f1[b * 1024 + o] = lrelu_(r + bf1[o]);
}

// ---- MLP 2: 1024 -> 1024 ----
__global__ __launch_bounds__(256) void k_mlp2(const float* __restrict__ x,
                        const float* __restrict__ W, const float* __restrict__ bias,
                        float* __restrict__ y){
  int b = blockIdx.x >> 4;
  int o = (blockIdx.x & 15) * 64 + (threadIdx.x >> 2);
  int q = threadIdx.x & 3;
  int k0 = q * 256;
  const float4* wr = (const float4*)(W + (size_t)o * 1024 + k0);
  const float4* xr = (const float4*)(x + b * 1024 + k0);
  float4 a = make_float4(0.f, 0.f, 0.f, 0.f);
  #pragma unroll 4
  for (int mI = 0; mI < 64; mI++){
    float4 wv = wr[mI], xv = xr[mI];
    a.x = fmaf(xv.x, wv.x, a.x);
    a.y = fmaf(xv.y, wv.y, a.y);
    a.z = fmaf(xv.z, wv.z, a.z);
    a.w = fmaf(xv.w, wv.w, a.w);
  }
  float r = a.x + a.y + a.z + a.w;
  r += __shfl_xor(r, 1, 64);
  r += __shfl_xor(r, 2, 64);
  if (q == 0) y[b * 1024 + o] = lrelu_(r + bias[o]);
}

// ---- MLP 3: 1024 -> 512 ----
__global__ __launch_bounds__(256) void k_mlp3(const float* __restrict__ x,
                        const float* __restrict__ W, const float* __restrict__ bias,
                        float* __restrict__ y){
  int b = blockIdx.x >> 3;
  int o = (blockIdx.x & 7) * 64 + (threadIdx.x >> 2);
  int q = threadIdx.x & 3;
  int k0 = q * 256;
  const float4* wr = (const float4*)(W + (size_t)o * 1024 + k0);
  const float4* xr = (const float4*)(x + b * 1024 + k0);
  float4 a = make_float4(0.f, 0.f, 0.f, 0.f);
  #pragma unroll 4
  for (int mI = 0; mI < 64; mI++){
    float4 wv = wr[mI], xv = xr[mI];
    a.x = fmaf(xv.x, wv.x, a.x);
    a.y = fmaf(xv.y, wv.y, a.y);
    a.z = fmaf(xv.z, wv.z, a.z);
    a.w = fmaf(xv.w, wv.w, a.w);
  }
  float r = a.x + a.y + a.z + a.w;
  r += __shfl_xor(r, 1, 64);
  r += __shfl_xor(r, 2, 64);
  if (q == 0) y[b * 512 + o] = lrelu_(r + bias[o]);
}

// ---- MLP out: 512 -> 2 ----
__global__ void k_mlp4(const float* __restrict__ f3, const float* __restrict__ Wo,
                       const float* __restrict__ bo, float* __restrict__ out){
  int tid = threadIdx.x;
  int g = tid >> 5, lane = tid & 31;
  int b = g >> 1, o = g & 1;
  const float4* xr = (const float4*)(f3 + b * 512);
  const float4* wr = (const float4*)(Wo + o * 512);
  float4 a = make_float4(0.f, 0.f, 0.f, 0.f);
  #pragma unroll
  for (int mI = 0; mI < 4; mI++){
    int k4 = lane + mI * 32;
    float4 xv = xr[k4], wv = wr[k4];
    a.x = fmaf(xv.x, wv.x, a.x);
    a.y = fmaf(xv.y, wv.y, a.y);
    a.z = fmaf(xv.z, wv.z, a.z);
    a.w = fmaf(xv.w, wv.w, a.w);
  }
  float r = a.x + a.y + a.z + a.w;
  for (int off = 16; off; off >>= 1) r += __shfl_xor(r, off, 64);
  if (lane == 0) out[b * 2 + o] = r + bo[o];
}

extern "C" void kernel_launch(void* const* d_in, const int* in_sizes, int n_in,
                              void* d_out, int out_size, void* d_ws, size_t ws_size,
                              hipStream_t stream) {
  const float* drug  = (const float*)d_in[0];
  const int*   natoms= (const int*)d_in[1];
  const int*   prot  = (const int*)d_in[2];
  const float* emb   = (const float*)d_in[3];
  const float* w1    = (const float*)d_in[4];
  const float* b1    = (const float*)d_in[5];
  const float* w2    = (const float*)d_in[6];
  const float* b2    = (const float*)d_in[7];
  const float* w3    = (const float*)d_in[8];
  const float* b3    = (const float*)d_in[9];
  const float* Wd    = (const float*)d_in[10];
  const float* bd    = (const float*)d_in[11];
  const float* Wp    = (const float*)d_in[12];
  const float* bp    = (const float*)d_in[13];
  const float* Watt  = (const float*)d_in[14];
  const float* batt  = (const float*)d_in[15];
  const float* W1    = (const float*)d_in[16];
  const float* bf1   = (const float*)d_in[17];
  const float* W2    = (const float*)d_in[18];
  const float* bf2   = (const float*)d_in[19];
  const float* W3    = (const float*)d_in[20];
  const float* bf3   = (const float*)d_in[21];
  const float* Wo    = (const float*)d_in[22];
  const float* bo    = (const float*)d_in[23];
  float* out = (float*)d_out;

  float* ws = (float*)d_ws;
  float* h1     = ws;                       // 160000 (reused later)
  float* cmeanT = ws;                       // 97280
  float* f1     = ws + 97280;               // 4096
  float* f2     = ws + 101376;              // 4096
  float* f3     = ws + 105472;              // 2048
  float* h2     = ws + 160000;              // 317440
  float* pconv  = ws + 477440;              // 627200
  float* dattT  = ws + 1104640;             // 97280
  float* pattT  = ws + 1201920;             // 629760
  float* pmeanT = ws + 1831680;             // 629760
  unsigned* enc = (unsigned*)(ws + 2461440);// 1280 u32
  float* projG  = ws + 2461760;             // 4186

  k_proj <<<17, 256, 0, stream>>>(emb, w1, projG);
  k_conv1<<<BB * 80, 256, 0, stream>>>(prot, projG, b1, h1);
  k_conv2<<<320, 256, 0, stream>>>(h1, w2, b2, h2);
  k_conv3<<<320, 256, 0, stream>>>(h2, w3, b3, pconv);
  k_dpatt<<<400, 256, 0, stream>>>(drug, natoms, prot, pconv, Wd, bd, Wp, bp,
                                   dattT, pattT, enc);
  k_means<<<BB * NC3, 256, 0, stream>>>(dattT, pattT, cmeanT, pmeanT);
  k_atte <<<400, 256, 0, stream>>>(cmeanT, pmeanT, Watt, batt, drug, pconv, enc);
  k_mlp1 <<<64, 256, 0, stream>>>(enc, W1, bf1, f1);
  k_mlp2 <<<64, 256, 0, stream>>>(f1, W2, bf2, f2);
  k_mlp3 <<<32, 256, 0, stream>>>(f2, W3, bf3, f3);
  k_mlp4 <<<1, 256, 0, stream>>>(f3, Wo, bo, out);
}